// Round 2
// baseline (849.524 us; speedup 1.0000x reference)
//
#include <hip/hip_runtime.h>
#include <math.h>

// Problem constants (KWinners2d: B=32, H=56, W=56, C=128)
#define NROW 32
#define NPR  401408        // elements per row = 56*56*128
#define N4   100352        // float4 per row
#define NCH  128
#define NBIN 4096
#define CAP  65536         // per-row candidate capacity (expected ~10k)
#define TCAP 2048          // tie capacity at exact threshold key

struct RowState { unsigned p1, krem1, tkey, cutoff; };

// workspace layout (bytes)
#define OFF_STATE 0                           // 32 * 16B
#define OFF_CNT   1024                        // 32 * 4B
#define OFF_HIST  2048                        // 32*4096*4 = 512KB
#define OFF_EQ    (OFF_HIST + 4*NBIN*NROW)    // 32*65536*8 = 16MB

__device__ __forceinline__ unsigned sortkey(float f) {
    unsigned u = __float_as_uint(f);
    return (u & 0x80000000u) ? ~u : (u | 0x80000000u);
}

// per-block boost factors: exp((k/n - duty[c]) * max(bs,0)), f32 ops + correctly
// rounded exp (double -> f32) to match XLA. 128 lanes, once per block: ~free.
__device__ __forceinline__ void load_boost(const float* duty, const float* bsp,
                                           const int* kp, float* bfs, int tid) {
    if (tid < NCH) {
        float bs = fmaxf(bsp[0], 0.0f);
        float td = (float)kp[0] / (float)NPR;
        bfs[tid] = (float)exp((double)((td - duty[tid]) * bs));
    }
    __syncthreads();
}

__global__ void k_zero(unsigned* p, int nwords) {
    int i = blockIdx.x * blockDim.x + threadIdx.x;
    if (i < nwords) p[i] = 0;
}

__global__ __launch_bounds__(256) void k_hist(const float* __restrict__ x,
                                              const float* __restrict__ duty,
                                              const float* __restrict__ bsp,
                                              const int* __restrict__ kp,
                                              unsigned* __restrict__ ghist) {
    __shared__ unsigned h[NBIN];
    __shared__ float bfs[NCH];
    int tid = threadIdx.x;
    for (int i = tid; i < NBIN; i += 256) h[i] = 0;
    load_boost(duty, bsp, kp, bfs, tid);

    int row = blockIdx.y;
    const int chunk = N4 / gridDim.x;
    const float4* xr = (const float4*)(x + (size_t)row * NPR) + (size_t)blockIdx.x * chunk;
    int base_j = blockIdx.x * chunk * 4;

    for (int i = tid; i < chunk; i += 256) {
        float4 v = xr[i];
        int c = (base_j + i * 4) & (NCH - 1);
        atomicAdd(&h[sortkey(v.x * bfs[c])     >> 20], 1u);
        atomicAdd(&h[sortkey(v.y * bfs[c + 1]) >> 20], 1u);
        atomicAdd(&h[sortkey(v.z * bfs[c + 2]) >> 20], 1u);
        atomicAdd(&h[sortkey(v.w * bfs[c + 3]) >> 20], 1u);
    }
    __syncthreads();
    unsigned* gh = ghist + (size_t)row * NBIN;
    for (int i = tid; i < NBIN; i += 256)
        if (h[i]) atomicAdd(&gh[i], h[i]);
}

__global__ __launch_bounds__(256) void k_scan(const unsigned* __restrict__ ghist,
                                              RowState* st, const int* kp) {
    __shared__ unsigned hh[NBIN];
    __shared__ unsigned psum[256];
    int row = blockIdx.x;
    int tid = threadIdx.x;
    const unsigned* gh = ghist + (size_t)row * NBIN;
    for (int i = tid; i < NBIN; i += 256) hh[i] = gh[i];
    __syncthreads();
    unsigned target = (unsigned)kp[0];

    unsigned s = 0;
    for (int q = 0; q < 16; ++q) s += hh[4095 - (tid * 16 + q)];
    psum[tid] = s;
    __syncthreads();
    if (tid == 0) {
        unsigned acc = 0;
        for (int t = 0; t < 256; ++t) { unsigned v = psum[t]; psum[t] = acc; acc += v; }
    }
    __syncthreads();
    unsigned cum = psum[tid];
    for (int q = 0; q < 16; ++q) {
        int bin = 4095 - (tid * 16 + q);
        unsigned cnt = hh[bin];
        if (cum < target && cum + cnt >= target) {
            st[row].p1 = (unsigned)bin;
            st[row].krem1 = target - cum;
        }
        cum += cnt;
    }
}

__global__ __launch_bounds__(256) void k_collect(const float* __restrict__ x,
                                                 const float* __restrict__ duty,
                                                 const float* __restrict__ bsp,
                                                 const int* __restrict__ kp,
                                                 const RowState* __restrict__ st,
                                                 unsigned* cnt, uint2* eq) {
    __shared__ float bfs[NCH];
    int tid = threadIdx.x;
    load_boost(duty, bsp, kp, bfs, tid);
    int row = blockIdx.y;
    unsigned p1 = st[row].p1;
    const int chunk = N4 / gridDim.x;
    const float4* xr = (const float4*)(x + (size_t)row * NPR) + (size_t)blockIdx.x * chunk;
    int base_j = blockIdx.x * chunk * 4;
    uint2* eqr = eq + (size_t)row * CAP;
    for (int i = tid; i < chunk; i += 256) {
        float4 v = xr[i];
        int j = base_j + i * 4;
        int c = j & (NCH - 1);
        unsigned kk[4] = { sortkey(v.x * bfs[c]),     sortkey(v.y * bfs[c + 1]),
                           sortkey(v.z * bfs[c + 2]), sortkey(v.w * bfs[c + 3]) };
#pragma unroll
        for (int t = 0; t < 4; ++t) {
            if ((kk[t] >> 20) == p1) {
                unsigned pos = atomicAdd(&cnt[row], 1u);
                if (pos < CAP) eqr[pos] = make_uint2((unsigned)(j + t), kk[t]);
            }
        }
    }
}

// One block per row. Level-2 hist (bits 19:8) + level-3 hist (bits 7:0) +
// exact tie-rank, all over the compact candidate list (~10k elems, L2-hot).
__global__ __launch_bounds__(256) void k_select(const unsigned* __restrict__ cnt,
                                                const uint2* __restrict__ eq,
                                                RowState* st) {
    __shared__ unsigned hA[NBIN];
    __shared__ unsigned hB[256];
    __shared__ unsigned psum[256];
    __shared__ unsigned tie[TCAP];
    __shared__ unsigned sh_p2, sh_krem2, sh_b0, sh_krem3, sh_tcnt;
    int row = blockIdx.x;
    int tid = threadIdx.x;
    unsigned m = min(cnt[row], (unsigned)CAP);
    unsigned q1 = st[row].krem1;
    const uint2* eqr = eq + (size_t)row * CAP;

    // level 2: bits [19:8]
    for (int i = tid; i < NBIN; i += 256) hA[i] = 0;
    __syncthreads();
    for (unsigned i = tid; i < m; i += 256)
        atomicAdd(&hA[(eqr[i].y >> 8) & 0xFFFu], 1u);
    __syncthreads();
    unsigned s = 0;
    for (int q = 0; q < 16; ++q) s += hA[4095 - (tid * 16 + q)];
    psum[tid] = s;
    __syncthreads();
    if (tid == 0) {
        unsigned acc = 0;
        for (int t = 0; t < 256; ++t) { unsigned v = psum[t]; psum[t] = acc; acc += v; }
    }
    __syncthreads();
    {
        unsigned cum = psum[tid];
        for (int q = 0; q < 16; ++q) {
            int bin = 4095 - (tid * 16 + q);
            unsigned c = hA[bin];
            if (cum < q1 && cum + c >= q1) { sh_p2 = (unsigned)bin; sh_krem2 = q1 - cum; }
            cum += c;
        }
    }
    __syncthreads();
    unsigned p2 = sh_p2, q2 = sh_krem2;

    // level 3: bits [7:0] within sub-bin p2
    if (tid < 256) hB[tid] = 0;
    if (tid == 0) sh_tcnt = 0;
    __syncthreads();
    for (unsigned i = tid; i < m; i += 256) {
        unsigned key = eqr[i].y;
        if (((key >> 8) & 0xFFFu) == p2) atomicAdd(&hB[key & 0xFFu], 1u);
    }
    __syncthreads();
    if (tid == 0) {
        unsigned cum = 0;
        for (int b = 255; b >= 0; --b) {
            unsigned c = hB[b];
            if (cum < q2 && cum + c >= q2) { sh_b0 = (unsigned)b; sh_krem3 = q2 - cum; break; }
            cum += c;
        }
    }
    __syncthreads();
    unsigned q3 = sh_krem3;
    unsigned p1 = st[row].p1;
    unsigned tkey = (p1 << 20) | (p2 << 8) | sh_b0;

    // exact ties at tkey: pick q3-th smallest index (top_k tie-break = lower idx)
    for (unsigned i = tid; i < m; i += 256) {
        if (eqr[i].y == tkey) {
            unsigned pos = atomicAdd(&sh_tcnt, 1u);
            if (pos < TCAP) tie[pos] = eqr[i].x;
        }
    }
    __syncthreads();
    unsigned t = min(sh_tcnt, (unsigned)TCAP);
    for (unsigned i = tid; i < t; i += 256) {
        unsigned mine = tie[i];
        unsigned rank = 0;
        for (unsigned j = 0; j < t; ++j) rank += (tie[j] < mine) ? 1u : 0u;
        if (rank == q3 - 1) {
            st[row].tkey = tkey;
            st[row].cutoff = mine;
        }
    }
}

__global__ __launch_bounds__(256) void k_mask(const float* __restrict__ x,
                                              const float* __restrict__ duty,
                                              const float* __restrict__ bsp,
                                              const int* __restrict__ kp,
                                              const RowState* __restrict__ st,
                                              float* __restrict__ out) {
    __shared__ float bfs[NCH];
    int tid = threadIdx.x;
    load_boost(duty, bsp, kp, bfs, tid);
    int row = blockIdx.y;
    unsigned tkey = st[row].tkey;
    unsigned cutoff = st[row].cutoff;
    const int chunk = N4 / gridDim.x;
    const float4* xr = (const float4*)(x + (size_t)row * NPR) + (size_t)blockIdx.x * chunk;
    float4* outr = (float4*)(out + (size_t)row * NPR) + (size_t)blockIdx.x * chunk;
    int base_j = blockIdx.x * chunk * 4;
    for (int i = tid; i < chunk; i += 256) {
        float4 v = xr[i];
        int j = base_j + i * 4;
        int c = j & (NCH - 1);
        unsigned k0 = sortkey(v.x * bfs[c]);
        unsigned k1 = sortkey(v.y * bfs[c + 1]);
        unsigned k2 = sortkey(v.z * bfs[c + 2]);
        unsigned k3 = sortkey(v.w * bfs[c + 3]);
        float4 o;
        o.x = (k0 > tkey || (k0 == tkey && (unsigned)(j + 0) <= cutoff)) ? v.x : 0.0f;
        o.y = (k1 > tkey || (k1 == tkey && (unsigned)(j + 1) <= cutoff)) ? v.y : 0.0f;
        o.z = (k2 > tkey || (k2 == tkey && (unsigned)(j + 2) <= cutoff)) ? v.z : 0.0f;
        o.w = (k3 > tkey || (k3 == tkey && (unsigned)(j + 3) <= cutoff)) ? v.w : 0.0f;
        outr[i] = o;
    }
}

extern "C" void kernel_launch(void* const* d_in, const int* in_sizes, int n_in,
                              void* d_out, int out_size, void* d_ws, size_t ws_size,
                              hipStream_t stream) {
    const float* x    = (const float*)d_in[0];
    const float* duty = (const float*)d_in[1];
    const float* bsp  = (const float*)d_in[2];
    const int*   kp   = (const int*)d_in[3];
    float* out = (float*)d_out;

    char* ws = (char*)d_ws;
    RowState* st  = (RowState*)(ws + OFF_STATE);
    unsigned* cnt = (unsigned*)(ws + OFF_CNT);
    unsigned* h1  = (unsigned*)(ws + OFF_HIST);
    uint2*    eq  = (uint2*)(ws + OFF_EQ);

    // zero cnt + hist (ws is poisoned 0xAA before every launch)
    {
        int nwords = (OFF_EQ - OFF_CNT) / 4;
        int nb = (nwords + 255) / 256;
        k_zero<<<nb, 256, 0, stream>>>((unsigned*)(ws + OFF_CNT), nwords);
    }

    dim3 g16(16, NROW);
    dim3 g32(32, NROW);
    k_hist<<<g16, 256, 0, stream>>>(x, duty, bsp, kp, h1);
    k_scan<<<NROW, 256, 0, stream>>>(h1, st, kp);
    k_collect<<<g16, 256, 0, stream>>>(x, duty, bsp, kp, st, cnt, eq);
    k_select<<<NROW, 256, 0, stream>>>(cnt, eq, st);
    k_mask<<<g32, 256, 0, stream>>>(x, duty, bsp, kp, st, out);
}

// Round 5
// 195.351 us; speedup vs baseline: 4.3487x; 4.3487x over previous
//
#include <hip/hip_runtime.h>
#include <math.h>

// Problem constants (KWinners2d: B=32, H=56, W=56, C=128)
#define NROW 32
#define NPR  401408        // elements per row = 56*56*128
#define N4   100352        // float4 per row
#define NCH  128
#define NBIN 4096
#define NBLK 16            // collect blocks per row
#define BCAP 4096          // per-block candidate slice capacity
#define TCAP 4096          // tie capacity at exact threshold key

struct RowState { unsigned p1, krem1, tkey, cutoff; };

// workspace layout (bytes)
#define OFF_STATE 0                           // 32 * 16B
#define OFF_BCNT  1024                        // 32*16 * 4B = 2KB
#define OFF_HIST  4096                        // 32*4096*4 = 512KB
#define OFF_EQ    (OFF_HIST + 4*NBIN*NROW)    // 32*16*4096*8 = 16MB

__device__ __forceinline__ unsigned sortkey(float f) {
    unsigned u = __float_as_uint(f);
    return (u & 0x80000000u) ? ~u : (u | 0x80000000u);
}

// per-block boost factors: exp((k/n - duty[c]) * max(bs,0)), f32 ops + correctly
// rounded exp (double -> f32) to match XLA. 128 lanes, once per block: ~free.
__device__ __forceinline__ void load_boost(const float* duty, const float* bsp,
                                           const int* kp, float* bfs, int tid) {
    if (tid < NCH) {
        float bs = fmaxf(bsp[0], 0.0f);
        float td = (float)kp[0] / (float)NPR;
        bfs[tid] = (float)exp((double)((td - duty[tid]) * bs));
    }
    __syncthreads();
}

__global__ void k_zero(unsigned* p, int nwords) {
    int i = blockIdx.x * blockDim.x + threadIdx.x;
    if (i < nwords) p[i] = 0;
}

__global__ __launch_bounds__(256) void k_hist(const float* __restrict__ x,
                                              const float* __restrict__ duty,
                                              const float* __restrict__ bsp,
                                              const int* __restrict__ kp,
                                              unsigned* __restrict__ ghist) {
    __shared__ unsigned h[NBIN];
    __shared__ float bfs[NCH];
    int tid = threadIdx.x;
    for (int i = tid; i < NBIN; i += 256) h[i] = 0;
    load_boost(duty, bsp, kp, bfs, tid);

    int row = blockIdx.y;
    const int chunk = N4 / gridDim.x;
    const float4* xr = (const float4*)(x + (size_t)row * NPR) + (size_t)blockIdx.x * chunk;
    int base_j = blockIdx.x * chunk * 4;

    for (int i = tid; i < chunk; i += 256) {
        float4 v = xr[i];
        int c = (base_j + i * 4) & (NCH - 1);
        atomicAdd(&h[sortkey(v.x * bfs[c])     >> 20], 1u);
        atomicAdd(&h[sortkey(v.y * bfs[c + 1]) >> 20], 1u);
        atomicAdd(&h[sortkey(v.z * bfs[c + 2]) >> 20], 1u);
        atomicAdd(&h[sortkey(v.w * bfs[c + 3]) >> 20], 1u);
    }
    __syncthreads();
    unsigned* gh = ghist + (size_t)row * NBIN;
    for (int i = tid; i < NBIN; i += 256)
        if (h[i]) atomicAdd(&gh[i], h[i]);
}

__global__ __launch_bounds__(256) void k_scan(const unsigned* __restrict__ ghist,
                                              RowState* st, const int* kp) {
    __shared__ unsigned hh[NBIN];
    __shared__ unsigned psum[256];
    int row = blockIdx.x;
    int tid = threadIdx.x;
    const unsigned* gh = ghist + (size_t)row * NBIN;
    for (int i = tid; i < NBIN; i += 256) hh[i] = gh[i];
    __syncthreads();
    unsigned target = (unsigned)kp[0];

    unsigned s = 0;
    for (int q = 0; q < 16; ++q) s += hh[4095 - (tid * 16 + q)];
    psum[tid] = s;
    __syncthreads();
    if (tid == 0) {
        unsigned acc = 0;
        for (int t = 0; t < 256; ++t) { unsigned v = psum[t]; psum[t] = acc; acc += v; }
    }
    __syncthreads();
    unsigned cum = psum[tid];
    for (int q = 0; q < 16; ++q) {
        int bin = 4095 - (tid * 16 + q);
        unsigned cnt = hh[bin];
        if (cum < target && cum + cnt >= target) {
            st[row].p1 = (unsigned)bin;
            st[row].krem1 = target - cum;
        }
        cum += cnt;
    }
}

// Per-block deterministic slices: LDS staging + ONE count write per block.
// No global atomics (round-2's 686us was a same-address global atomic storm).
__global__ __launch_bounds__(256) void k_collect(const float* __restrict__ x,
                                                 const float* __restrict__ duty,
                                                 const float* __restrict__ bsp,
                                                 const int* __restrict__ kp,
                                                 const RowState* __restrict__ st,
                                                 unsigned* __restrict__ bcnt,
                                                 uint2* __restrict__ eq) {
    __shared__ float bfs[NCH];
    __shared__ uint2 sbuf[BCAP];
    __shared__ unsigned scnt;
    int tid = threadIdx.x;
    if (tid == 0) scnt = 0;
    load_boost(duty, bsp, kp, bfs, tid);   // includes __syncthreads()

    int row = blockIdx.y;
    int bx = blockIdx.x;
    unsigned p1 = st[row].p1;
    const int chunk = N4 / NBLK;
    const float4* xr = (const float4*)(x + (size_t)row * NPR) + (size_t)bx * chunk;
    int base_j = bx * chunk * 4;
    for (int i = tid; i < chunk; i += 256) {
        float4 v = xr[i];
        int j = base_j + i * 4;
        int c = j & (NCH - 1);
        unsigned kk[4] = { sortkey(v.x * bfs[c]),     sortkey(v.y * bfs[c + 1]),
                           sortkey(v.z * bfs[c + 2]), sortkey(v.w * bfs[c + 3]) };
#pragma unroll
        for (int t = 0; t < 4; ++t) {
            if ((kk[t] >> 20) == p1) {
                unsigned pos = atomicAdd(&scnt, 1u);   // LDS atomic only
                if (pos < BCAP) sbuf[pos] = make_uint2((unsigned)(j + t), kk[t]);
            }
        }
    }
    __syncthreads();
    unsigned m = min(scnt, (unsigned)BCAP);
    uint2* slice = eq + ((size_t)row * NBLK + bx) * BCAP;
    for (unsigned i = tid; i < m; i += 256) slice[i] = sbuf[i];   // coalesced flush
    if (tid == 0) bcnt[row * NBLK + bx] = m;
}

// One block per row. Level-2 hist (bits 19:8) + level-3 hist (bits 7:0) +
// exact tie-rank, over the compact per-block slices (~L2-hot).
__global__ __launch_bounds__(256) void k_select(const unsigned* __restrict__ bcnt,
                                                const uint2* __restrict__ eq,
                                                RowState* st) {
    __shared__ unsigned hA[NBIN];
    __shared__ unsigned hB[256];
    __shared__ unsigned psum[256];
    __shared__ unsigned tie[TCAP];
    __shared__ unsigned sh_p2, sh_krem2, sh_b0, sh_krem3, sh_tcnt;
    int row = blockIdx.x;
    int tid = threadIdx.x;
    unsigned q1 = st[row].krem1;
    const uint2* eqr = eq + (size_t)row * NBLK * BCAP;
    const unsigned* bc = bcnt + row * NBLK;

    // level 2: bits [19:8]
    for (int i = tid; i < NBIN; i += 256) hA[i] = 0;
    __syncthreads();
    for (int s = 0; s < NBLK; ++s) {
        unsigned m = bc[s];
        const uint2* sl = eqr + (size_t)s * BCAP;
        for (unsigned i = tid; i < m; i += 256)
            atomicAdd(&hA[(sl[i].y >> 8) & 0xFFFu], 1u);
    }
    __syncthreads();
    unsigned s0 = 0;
    for (int q = 0; q < 16; ++q) s0 += hA[4095 - (tid * 16 + q)];
    psum[tid] = s0;
    __syncthreads();
    if (tid == 0) {
        unsigned acc = 0;
        for (int t = 0; t < 256; ++t) { unsigned v = psum[t]; psum[t] = acc; acc += v; }
    }
    __syncthreads();
    {
        unsigned cum = psum[tid];
        for (int q = 0; q < 16; ++q) {
            int bin = 4095 - (tid * 16 + q);
            unsigned c = hA[bin];
            if (cum < q1 && cum + c >= q1) { sh_p2 = (unsigned)bin; sh_krem2 = q1 - cum; }
            cum += c;
        }
    }
    __syncthreads();
    unsigned p2 = sh_p2, q2 = sh_krem2;

    // level 3: bits [7:0] within sub-bin p2
    if (tid < 256) hB[tid] = 0;
    if (tid == 0) sh_tcnt = 0;
    __syncthreads();
    for (int s = 0; s < NBLK; ++s) {
        unsigned m = bc[s];
        const uint2* sl = eqr + (size_t)s * BCAP;
        for (unsigned i = tid; i < m; i += 256) {
            unsigned key = sl[i].y;
            if (((key >> 8) & 0xFFFu) == p2) atomicAdd(&hB[key & 0xFFu], 1u);
        }
    }
    __syncthreads();
    if (tid == 0) {
        unsigned cum = 0;
        for (int b = 255; b >= 0; --b) {
            unsigned c = hB[b];
            if (cum < q2 && cum + c >= q2) { sh_b0 = (unsigned)b; sh_krem3 = q2 - cum; break; }
            cum += c;
        }
    }
    __syncthreads();
    unsigned q3 = sh_krem3;
    unsigned p1 = st[row].p1;
    unsigned tkey = (p1 << 20) | (p2 << 8) | sh_b0;

    // exact ties at tkey: pick q3-th smallest index (top_k tie-break = lower idx)
    for (int s = 0; s < NBLK; ++s) {
        unsigned m = bc[s];
        const uint2* sl = eqr + (size_t)s * BCAP;
        for (unsigned i = tid; i < m; i += 256) {
            if (sl[i].y == tkey) {
                unsigned pos = atomicAdd(&sh_tcnt, 1u);
                if (pos < TCAP) tie[pos] = sl[i].x;
            }
        }
    }
    __syncthreads();
    unsigned t = min(sh_tcnt, (unsigned)TCAP);
    for (unsigned i = tid; i < t; i += 256) {
        unsigned mine = tie[i];
        unsigned rank = 0;
        for (unsigned j = 0; j < t; ++j) rank += (tie[j] < mine) ? 1u : 0u;
        if (rank == q3 - 1) {
            st[row].tkey = tkey;
            st[row].cutoff = mine;
        }
    }
}

__global__ __launch_bounds__(256) void k_mask(const float* __restrict__ x,
                                              const float* __restrict__ duty,
                                              const float* __restrict__ bsp,
                                              const int* __restrict__ kp,
                                              const RowState* __restrict__ st,
                                              float* __restrict__ out) {
    __shared__ float bfs[NCH];
    int tid = threadIdx.x;
    load_boost(duty, bsp, kp, bfs, tid);
    int row = blockIdx.y;
    unsigned tkey = st[row].tkey;
    unsigned cutoff = st[row].cutoff;
    const int chunk = N4 / gridDim.x;
    const float4* xr = (const float4*)(x + (size_t)row * NPR) + (size_t)blockIdx.x * chunk;
    float4* outr = (float4*)(out + (size_t)row * NPR) + (size_t)blockIdx.x * chunk;
    int base_j = blockIdx.x * chunk * 4;
    for (int i = tid; i < chunk; i += 256) {
        float4 v = xr[i];
        int j = base_j + i * 4;
        int c = j & (NCH - 1);
        unsigned k0 = sortkey(v.x * bfs[c]);
        unsigned k1 = sortkey(v.y * bfs[c + 1]);
        unsigned k2 = sortkey(v.z * bfs[c + 2]);
        unsigned k3 = sortkey(v.w * bfs[c + 3]);
        float4 o;
        o.x = (k0 > tkey || (k0 == tkey && (unsigned)(j + 0) <= cutoff)) ? v.x : 0.0f;
        o.y = (k1 > tkey || (k1 == tkey && (unsigned)(j + 1) <= cutoff)) ? v.y : 0.0f;
        o.z = (k2 > tkey || (k2 == tkey && (unsigned)(j + 2) <= cutoff)) ? v.z : 0.0f;
        o.w = (k3 > tkey || (k3 == tkey && (unsigned)(j + 3) <= cutoff)) ? v.w : 0.0f;
        outr[i] = o;
    }
}

extern "C" void kernel_launch(void* const* d_in, const int* in_sizes, int n_in,
                              void* d_out, int out_size, void* d_ws, size_t ws_size,
                              hipStream_t stream) {
    const float* x    = (const float*)d_in[0];
    const float* duty = (const float*)d_in[1];
    const float* bsp  = (const float*)d_in[2];
    const int*   kp   = (const int*)d_in[3];
    float* out = (float*)d_out;

    char* ws = (char*)d_ws;
    RowState* st   = (RowState*)(ws + OFF_STATE);
    unsigned* bcnt = (unsigned*)(ws + OFF_BCNT);
    unsigned* h1   = (unsigned*)(ws + OFF_HIST);
    uint2*    eq   = (uint2*)(ws + OFF_EQ);

    // zero only the histogram (ws is poisoned 0xAA before every launch)
    {
        int nwords = NROW * NBIN;
        int nb = (nwords + 255) / 256;
        k_zero<<<nb, 256, 0, stream>>>(h1, nwords);
    }

    dim3 g16(NBLK, NROW);
    dim3 g32(32, NROW);
    k_hist<<<g16, 256, 0, stream>>>(x, duty, bsp, kp, h1);
    k_scan<<<NROW, 256, 0, stream>>>(h1, st, kp);
    k_collect<<<g16, 256, 0, stream>>>(x, duty, bsp, kp, st, bcnt, eq);
    k_select<<<NROW, 256, 0, stream>>>(bcnt, eq, st);
    k_mask<<<g32, 256, 0, stream>>>(x, duty, bsp, kp, st, out);
}